// Round 12
// baseline (187.555 us; speedup 1.0000x reference)
//
#include <hip/hip_runtime.h>

#define SIG0 0.17f
#define SIG1 4.86f

__device__ __constant__ float c_filt0[25] = {
  0.04f,0.04f,0.05f,0.04f,0.04f,
  0.04f,0.03f,0.04f,0.03f,0.04f,
  0.05f,0.04f,0.05f,0.04f,0.05f,
  0.04f,0.03f,0.04f,0.03f,0.04f,
  0.04f,0.04f,0.05f,0.04f,0.04f};
__device__ __constant__ float c_f1d[5] = {0.05f,0.25f,0.4f,0.25f,0.05f};

static __device__ __forceinline__ int iclamp(int v, int lo, int hi){
  return v < lo ? lo : (v > hi ? hi : v);
}
static __device__ __forceinline__ float4 gamma4(float4 v){
  const float e = 0.3846153846153846f;
  v.x = __powf(v.x, e); v.y = __powf(v.y, e);
  v.z = __powf(v.z, e); v.w = __powf(v.w, e);
  return v;
}

// Padded level buffers: size S stored (S+4) x (S+8); logical (y,x) at [(y+2)*(S+8)+(x+4)].
// g1: S=256 stride 264 (img 68640); g2: S=128 stride 136 (17952); g3: S=64 stride 72 (4896)

// ================= k_d1: gamma + down0. out tile 256 wide x 8 tall. grid (32 yt, 32 img) ======
__global__ __launch_bounds__(256)
void k_d1(const float* __restrict__ hin, const float* __restrict__ lin,
          float* __restrict__ g1){
  extern __shared__ float sm[];
  float* ST = sm;            // [20][520]
  float* HS = sm + 20*520;   // [20][256]
  int bx = blockIdx.x, z = blockIdx.y;
  const float* in = (z<16)? hin + (size_t)z*262144 : lin + (size_t)(z-16)*262144;
  float* out0 = g1 + (size_t)z*68640;
  int t = threadIdx.x;
  for (int f=t; f<2560; f+=256){             // 20 rows x 128 chunks
    int r = f>>7, ch = f&127;
    int yy = iclamp(16*bx-2+r, 0, 511);
    float4 v = *(const float4*)&in[(size_t)yy*512 + 4*ch];
    *(float4*)&ST[r*520 + 4 + 4*ch] = gamma4(v);
  }
  __syncthreads();
  if (t < 20){
    float vl = ST[t*520 + 4],  vr = ST[t*520 + 515];
    float4 v4l = {vl,vl,vl,vl}, v4r = {vr,vr,vr,vr};
    *(float4*)&ST[t*520 + 0]   = v4l;
    *(float4*)&ST[t*520 + 516] = v4r;
  }
  __syncthreads();
  for (int f=t; f<5120; f+=256){             // 20 x 256 h-pass
    int r = f>>8, xo = f&255;
    const float* rp = &ST[r*520 + 2*xo + 2];
    HS[r*256 + xo] = 0.05f*rp[0]+0.25f*rp[1]+0.4f*rp[2]+0.25f*rp[3]+0.05f*rp[4];
  }
  __syncthreads();
  for (int f=t; f<2048; f+=256){             // 8 x 256 v-pass + padded write
    int yo = f>>8, X = f&255;
    int Y = 8*bx + yo;
    float v = 0.05f*HS[(2*yo)*256+X]+0.25f*HS[(2*yo+1)*256+X]+0.4f*HS[(2*yo+2)*256+X]
            +0.25f*HS[(2*yo+3)*256+X]+0.05f*HS[(2*yo+4)*256+X];
    int rlo=(Y==0)?0:(Y+2), rhi=(Y==255)?259:(Y+2);
    int clo=(X==0)?0:(X+4), chi=(X==255)?263:(X+4);
    for (int rr=rlo; rr<=rhi; rr++)
      for (int cc=clo; cc<=chi; cc++)
        out0[(size_t)rr*264+cc] = v;
  }
}

// ================= generic down: padded in (SIN) -> padded out (SIN/2). tile SO x 8 ==========
template<int SIN>
__global__ __launch_bounds__(256)
void k_down(const float* __restrict__ gin, float* __restrict__ gout){
  constexpr int WI = SIN+8, SO = SIN/2, PO = SO+8;
  constexpr int CH = WI/4;
  extern __shared__ float sm[];
  float* ST = sm;              // [20][WI]
  float* HS = sm + 20*WI;      // [20][SO]
  int bx = blockIdx.x, z = blockIdx.y;
  const float* in0 = gin + (size_t)z * (size_t)((SIN+4)*WI);
  float* out0 = gout + (size_t)z * (size_t)((SO+4)*PO);
  int t = threadIdx.x;
  for (int f=t; f<20*CH; f+=256){
    int r = f/CH, ch = f - r*CH;
    *(float4*)&ST[r*WI + 4*ch] = *(const float4*)&in0[(size_t)(16*bx + r)*WI + 4*ch];
  }
  __syncthreads();
  for (int f=t; f<20*SO; f+=256){
    int r = f/SO, xo = f - r*SO;
    const float* rp = &ST[r*WI + 2*xo + 2];
    HS[r*SO + xo] = 0.05f*rp[0]+0.25f*rp[1]+0.4f*rp[2]+0.25f*rp[3]+0.05f*rp[4];
  }
  __syncthreads();
  for (int f=t; f<8*SO; f+=256){
    int yo = f/SO, X = f - yo*SO;
    int Y = 8*bx + yo;
    float v = 0.05f*HS[(2*yo)*SO+X]+0.25f*HS[(2*yo+1)*SO+X]+0.4f*HS[(2*yo+2)*SO+X]
            +0.25f*HS[(2*yo+3)*SO+X]+0.05f*HS[(2*yo+4)*SO+X];
    int rlo=(Y==0)?0:(Y+2), rhi=(Y==SO-1)?(SO+3):(Y+2);
    int clo=(X==0)?0:(X+4), chi=(X==SO-1)?(SO+7):(X+4);
    for (int rr=rlo; rr<=rhi; rr++)
      for (int cc=clo; cc<=chi; cc++)
        out0[(size_t)rr*PO+cc] = v;
  }
}

// ================= fused body: lap + fixes + den + diff + reduce ===========================
// GAMMA=1: a0/a1 raw SIMGxSIMG inputs; GAMMA=0: a0/a1 padded buffers (stride SIMG+8, TW==SIMG).
template<int GAMMA, int SIMG, int TW, int TH>
__device__ __forceinline__ void fused_body(
    const float* __restrict__ a0, const float* __restrict__ a1,
    const float* __restrict__ s10, const float* __restrict__ s11,
    int xt, int yt, float* __restrict__ out_slot)
{
  constexpr int WL  = TW + 8;         // sg row length
  constexpr int W1L = TW/2 + 8;       // s1 LDS row length
  constexpr int PS1 = SIMG/2 + 8;     // s1 BUFFER stride
  constexpr int NR  = TH + 4;         // sg rows
  constexpr int NR1 = TH/2 + 4;       // s1 rows
  constexpr int PRS = NR/2;           // p2 row pairs
  constexpr int NSEG= WL/8;           // p2 col segs (33/17)
  constexpr int NQX = TW/4;
  constexpr int LQX = (NQX==64)?6:5;
  constexpr int QY  = TH/2;
  constexpr int CH  = WL/4;
  constexpr int CH1 = W1L/4;
  extern __shared__ float sm[];
  float* SG  = sm;                    // [2][NR][WL]
  float* S1L = sm + 2*NR*WL;          // [2][NR1][W1L]
  float* RED = S1L + 2*NR1*W1L;       // [4]
  const int t = threadIdx.x;
  const int x0 = TW*xt, y0 = TH*yt;

  // ---- p1a: stage sg (contiguous f4 chunks per row) ----
  if (GAMMA){
    for (int f=t; f<2*NR*CH; f+=256){
      int img = f >= NR*CH; int rem = img ? f - NR*CH : f;
      int rr = rem/CH, ch = rem - rr*CH;
      int yy = iclamp(y0-2+rr, 0, SIMG-1);
      int xb = x0 - 4 + 4*ch;
      const float* rp = (img ? a1 : a0) + (size_t)yy*SIMG;
      float4 v;
      if (xb >= 0 && xb <= SIMG-4) v = *(const float4*)&rp[xb];
      else { v.x=rp[iclamp(xb,0,SIMG-1)]; v.y=rp[iclamp(xb+1,0,SIMG-1)];
             v.z=rp[iclamp(xb+2,0,SIMG-1)]; v.w=rp[iclamp(xb+3,0,SIMG-1)]; }
      *(float4*)&SG[(img*NR+rr)*WL + 4*ch] = gamma4(v);
    }
  } else {
    for (int f=t; f<2*NR*CH; f+=256){
      int img = f >= NR*CH; int rem = img ? f - NR*CH : f;
      int rr = rem/CH, ch = rem - rr*CH;
      const float* src = img ? a1 : a0;
      *(float4*)&SG[(img*NR+rr)*WL + 4*ch] =
          *(const float4*)&src[(size_t)(y0+rr)*WL + 4*ch];
    }
  }
  // ---- p1b: stage s1 ----
  for (int f=t; f<2*NR1*CH1; f+=256){
    int img = f >= NR1*CH1; int rem = img ? f - NR1*CH1 : f;
    int ro = rem/CH1, ch = rem - ro*CH1;
    const float* src = img ? s11 : s10;
    *(float4*)&S1L[(img*NR1+ro)*W1L + 4*ch] =
        *(const float4*)&src[(size_t)(y0/2+ro)*PS1 + x0/2 + 4*ch];
  }
  __syncthreads();

  // ---- p2: lap in place; unit = (img, row-pair p, 8-col seg q); covers ALL sg cols ----
  for (int f=t; f<2*PRS*NSEG; f+=256){
    int img = f >= PRS*NSEG; int rem = img ? f - PRS*NSEG : f;
    int p = rem/NSEG, q = rem - p*NSEG;
    const float* s1b = S1L + img*NR1*W1L;
    float A[8], B[8], C[8];
    { const float* pr = s1b + p*W1L + 4*q;
      *(float4*)&A[0]=*(const float4*)&pr[0]; *(float4*)&A[4]=*(const float4*)&pr[4]; }
    { const float* pr = s1b + (p+1)*W1L + 4*q;
      *(float4*)&B[0]=*(const float4*)&pr[0]; *(float4*)&B[4]=*(const float4*)&pr[4]; }
    { const float* pr = s1b + (p+2)*W1L + 4*q;
      *(float4*)&C[0]=*(const float4*)&pr[0]; *(float4*)&C[4]=*(const float4*)&pr[4]; }
    float ue[8], uo[8];
    #pragma unroll
    for (int j=0;j<4;j++){
      float hEA = 0.05f*A[j+1]+0.4f*A[j+2]+0.05f*A[j+3];
      float hEB = 0.05f*B[j+1]+0.4f*B[j+2]+0.05f*B[j+3];
      float hEC = 0.05f*C[j+1]+0.4f*C[j+2]+0.05f*C[j+3];
      float hOA = 0.25f*(A[j+2]+A[j+3]);
      float hOB = 0.25f*(B[j+2]+B[j+3]);
      float hOC = 0.25f*(C[j+2]+C[j+3]);
      ue[2*j]   = 0.2f*hEA + 1.6f*hEB + 0.2f*hEC;
      ue[2*j+1] = 0.2f*hOA + 1.6f*hOB + 0.2f*hOC;
      uo[2*j]   = hEB + hEC;
      uo[2*j+1] = hOB + hOC;
    }
    float* re = SG + (img*NR + 2*p)*WL + 8*q;
    float* ro_ = SG + (img*NR + 2*p+1)*WL + 8*q;
    float ve[8], vo[8];
    *(float4*)&ve[0]=*(float4*)&re[0]; *(float4*)&ve[4]=*(float4*)&re[4];
    *(float4*)&vo[0]=*(float4*)&ro_[0]; *(float4*)&vo[4]=*(float4*)&ro_[4];
    #pragma unroll
    for (int j=0;j<8;j++){ ve[j] -= ue[j]; vo[j] -= uo[j]; }
    *(float4*)&re[0]=*(float4*)&ve[0]; *(float4*)&re[4]=*(float4*)&ve[4];
    *(float4*)&ro_[0]=*(float4*)&vo[0]; *(float4*)&ro_[4]=*(float4*)&vo[4];
  }
  __syncthreads();

  // ---- replicate fixes: rows (img y-edges), then cols (img x-edges) ----
  {
    bool top = (y0 == 0), bot = (y0 + TH == SIMG);
    if (top | bot){
      for (int f=t; f<2*CH; f+=256){
        int img = f >= CH; int ch = img ? f - CH : f;
        float* base = SG + img*NR*WL;
        if (top){ float4 v = *(float4*)&base[2*WL + 4*ch];
          *(float4*)&base[0*WL + 4*ch] = v; *(float4*)&base[1*WL + 4*ch] = v; }
        if (bot){ float4 v = *(float4*)&base[(TH+1)*WL + 4*ch];
          *(float4*)&base[(TH+2)*WL + 4*ch] = v; *(float4*)&base[(TH+3)*WL + 4*ch] = v; }
      }
    }
  }
  __syncthreads();
  {
    bool lft = (x0 == 0), rgt = (x0 + TW == SIMG);
    if ((lft | rgt) && t < 2*NR){
      int img = t >= NR; int r = img ? t - NR : t;
      float* row = SG + (img*NR + r)*WL;
      if (lft){ float v = row[4];    float4 v4 = {v,v,v,v}; *(float4*)&row[0]    = v4; }
      if (rgt){ float v = row[WL-5]; float4 v4 = {v,v,v,v}; *(float4*)&row[WL-4] = v4; }
    }
  }
  __syncthreads();

  // ---- p3: box-trick den conv + diff. unit = (img, qx, qy) 4x2 quad ----
  float vacc = 0.f;
  constexpr int P3N = 2*NQX*QY;
  for (int k=0; k<P3N/256; k++){
    int u = t + 256*k;
    int img = u & 1;
    int quad = u >> 1;
    int qx = quad & (NQX-1);
    int qy = quad >> LQX;
    const float* sgb = SG + img*NR*WL;
    int cb = 4*qx, rb = 2*qy;
    float T0[4]={0,0,0,0}, T1[4]={0,0,0,0};
    float s5a[4], s5b[4], s3a[4], s3b[4], n0[4], n1[4];
    #pragma unroll
    for (int r=0;r<6;r++){
      float w[12];
      const float* rp = &sgb[(rb+r)*WL + cb];
      *(float4*)&w[0]=*(const float4*)&rp[0];
      *(float4*)&w[4]=*(const float4*)&rp[4];
      *(float4*)&w[8]=*(const float4*)&rp[8];
      float aw[8];
      #pragma unroll
      for (int j=0;j<8;j++) aw[j] = fabsf(w[j+2]);
      float h0 = ((aw[0]+aw[1])+(aw[2]+aw[3]))+aw[4];
      float h1 = h0 - aw[0] + aw[5];
      float h2 = h1 - aw[1] + aw[6];
      float h3 = h2 - aw[2] + aw[7];
      float hh[4] = {h0,h1,h2,h3};
      if (r<=4){
        #pragma unroll
        for (int c=0;c<4;c++) T0[c] += hh[c];
      }
      if (r>=1){
        #pragma unroll
        for (int c=0;c<4;c++) T1[c] += hh[c];
      }
      if (r==0){
        for (int c=0;c<4;c++) s5a[c] = aw[c+2];
      }
      if (r==1){
        for (int c=0;c<4;c++){ s3a[c] = aw[c+1]+aw[c+3]; s5b[c] = aw[c+2]; }
      }
      if (r==2){
        for (int c=0;c<4;c++){ s5a[c] += aw[c]+aw[c+2]+aw[c+4]; n0[c]=w[c+4]; s3b[c] = aw[c+1]+aw[c+3]; }
      }
      if (r==3){
        for (int c=0;c<4;c++){ s3a[c] += aw[c+1]+aw[c+3]; s5b[c] += aw[c]+aw[c+2]+aw[c+4]; n1[c]=w[c+4]; }
      }
      if (r==4){
        for (int c=0;c<4;c++){ s5a[c] += aw[c+2]; s3b[c] += aw[c+1]+aw[c+3]; }
      }
      if (r==5){
        for (int c=0;c<4;c++) s5b[c] += aw[c+2];
      }
    }
    float qv[8];
    #pragma unroll
    for (int c=0;c<4;c++){
      float d0 = SIG0 + 0.04f*T0[c] + 0.01f*s5a[c] - 0.01f*s3a[c];
      float d1 = SIG0 + 0.04f*T1[c] + 0.01f*s5b[c] - 0.01f*s3b[c];
      qv[c]   = __fdividef(n0[c], d0);
      qv[4+c] = __fdividef(n1[c], d1);
    }
    #pragma unroll
    for (int i=0;i<8;i++){
      float o = __shfl_xor(qv[i], 1);
      float d = qv[i] - o;
      vacc += d*d;
    }
  }
  if (t & 1) vacc = 0.f;   // count each img pair once
  #pragma unroll
  for (int off=32; off>0; off>>=1) vacc += __shfl_down(vacc, off);
  if ((t&63)==0) RED[t>>6] = vacc;
  __syncthreads();
  if (t==0)
    out_slot[0] = RED[0]+RED[1]+RED[2]+RED[3];
}

// ---- fused wrappers ----
__global__ __launch_bounds__(256)
void k_fused0(const float* __restrict__ h, const float* __restrict__ l,
              const float* __restrict__ g1, float* __restrict__ p0){
  int xt = blockIdx.x, yt = blockIdx.y, z = blockIdx.z;
  fused_body<1,512,256,16>(h + (size_t)z*262144, l + (size_t)z*262144,
                           g1 + (size_t)z*68640, g1 + (size_t)(z+16)*68640,
                           xt, yt, p0 + z*64 + yt*2 + xt);
}
__global__ __launch_bounds__(256)
void k_fused1(const float* __restrict__ g1, const float* __restrict__ g2,
              float* __restrict__ p1){
  int yt = blockIdx.x, z = blockIdx.y;
  fused_body<0,256,256,8>(g1 + (size_t)z*68640, g1 + (size_t)(z+16)*68640,
                          g2 + (size_t)z*17952, g2 + (size_t)(z+16)*17952,
                          0, yt, p1 + z*32 + yt);
}
__global__ __launch_bounds__(256)
void k_fused2(const float* __restrict__ g2, const float* __restrict__ g3,
              float* __restrict__ p2s){
  int yt = blockIdx.x, z = blockIdx.y;
  fused_body<0,128,128,8>(g2 + (size_t)z*17952, g2 + (size_t)(z+16)*17952,
                          g3 + (size_t)z*4896, g3 + (size_t)(z+16)*4896,
                          0, yt, p2s + z*16 + yt);
}

// ================= tail (levels 3..6) =================
struct TS {
  float A3[2][64][66];
  float A4[2][32][34];
  float A5[2][16][18];
  float A6[2][8][10];
  float red[4];
};

static __device__ __forceinline__ void down_lds(const float* Ain, int ldi, int Sin,
                                                float* Aout, int ldo, int Sout,
                                                int tid, int NT){
  int tot = 2*Sout*Sout;
  for (int f=tid; f<tot; f+=NT){
    int img = f/(Sout*Sout), rem = f%(Sout*Sout), y=rem/Sout, x=rem%Sout;
    const float* A = Ain + img*Sin*ldi;
    float s=0.f;
    #pragma unroll
    for (int i=0;i<5;i++){
      int yy=iclamp(2*y+i-2,0,Sin-1);
      float rs=0.f;
      #pragma unroll
      for (int j=0;j<5;j++){
        int xx=iclamp(2*x+j-2,0,Sin-1);
        rs += c_f1d[j]*A[yy*ldi+xx];
      }
      s += c_f1d[i]*rs;
    }
    Aout[img*Sout*ldo + y*ldo + x] = s;
  }
}
static __device__ __forceinline__ void lap_lds(float* Ak, int ldk, int S,
                                               const float* Ag, int ldg,
                                               int tid, int NT){
  int Sg = S>>1;
  int tot = 2*S*S;
  for (int f=tid; f<tot; f+=NT){
    int img=f/(S*S), rem=f%(S*S), y=rem/S, x=rem%S;
    const float* G = Ag + img*Sg*ldg;
    int y2=y>>1, x2=x>>1;
    int ry0,ry1,ry2; float wy0,wy1,wy2;
    if (!(y&1)){ ry0=iclamp(y2-1,0,Sg-1); ry1=y2; ry2=iclamp(y2+1,0,Sg-1); wy0=0.2f; wy1=1.6f; wy2=0.2f; }
    else { ry0=y2; ry1=iclamp(y2+1,0,Sg-1); ry2=y2; wy0=1.f; wy1=1.f; wy2=0.f; }
    int cx0,cx1,cx2; float wx0,wx1,wx2;
    if (!(x&1)){ cx0=iclamp(x2-1,0,Sg-1); cx1=x2; cx2=iclamp(x2+1,0,Sg-1); wx0=0.05f; wx1=0.4f; wx2=0.05f; }
    else { cx0=x2; cx1=iclamp(x2+1,0,Sg-1); cx2=x2; wx0=0.25f; wx1=0.25f; wx2=0.f; }
    float u0 = wx0*G[ry0*ldg+cx0]+wx1*G[ry0*ldg+cx1]+wx2*G[ry0*ldg+cx2];
    float u1 = wx0*G[ry1*ldg+cx0]+wx1*G[ry1*ldg+cx1]+wx2*G[ry1*ldg+cx2];
    float u2 = wx0*G[ry2*ldg+cx0]+wx1*G[ry2*ldg+cx1]+wx2*G[ry2*ldg+cx2];
    Ak[img*S*ldk + y*ldk + x] -= wy0*u0+wy1*u1+wy2*u2;
  }
}
static __device__ __forceinline__ float diff_lds(const float* A, int ld, int S,
                                                 int tid, int NT){
  float v=0.f;
  const float* Ah = A;
  const float* Al = A + S*ld;
  for (int f=tid; f<S*S; f+=NT){
    int y=f/S, x=f%S;
    float dh=SIG0, dl=SIG0;
    #pragma unroll
    for (int i=0;i<5;i++){
      int yy=iclamp(y+i-2,0,S-1);
      #pragma unroll
      for (int j=0;j<5;j++){
        int xx=iclamp(x+j-2,0,S-1);
        float w=c_filt0[i*5+j];
        dh += w*fabsf(Ah[yy*ld+xx]);
        dl += w*fabsf(Al[yy*ld+xx]);
      }
    }
    float d = __fdividef(Ah[y*ld+x],dh) - __fdividef(Al[y*ld+x],dl);
    v += d*d;
  }
  return v;
}

__global__ __launch_bounds__(256)
void k_tail(const float* __restrict__ g3, float* __restrict__ accum){
  extern __shared__ char smem[];
  TS* T = (TS*)smem;
  int b = blockIdx.x;
  int tid = threadIdx.x;
  const float* s0  = g3 + (size_t)b*4896 + 148;
  const float* s1p = g3 + (size_t)(b+16)*4896 + 148;
  for (int f=tid; f<2*4096; f+=256){
    int img=f>>12, rem=f&4095, r=rem>>6, c=rem&63;
    T->A3[img][r][c] = (img? s1p : s0)[(size_t)r*72+c];
  }
  __syncthreads();
  down_lds(&T->A3[0][0][0],66,64,&T->A4[0][0][0],34,32,tid,256);
  __syncthreads();
  down_lds(&T->A4[0][0][0],34,32,&T->A5[0][0][0],18,16,tid,256);
  __syncthreads();
  down_lds(&T->A5[0][0][0],18,16,&T->A6[0][0][0],10,8,tid,256);
  __syncthreads();
  lap_lds(&T->A3[0][0][0],66,64,&T->A4[0][0][0],34,tid,256);
  __syncthreads();
  float v3 = diff_lds(&T->A3[0][0][0],66,64,tid,256);
  lap_lds(&T->A4[0][0][0],34,32,&T->A5[0][0][0],18,tid,256);
  __syncthreads();
  float v4 = diff_lds(&T->A4[0][0][0],34,32,tid,256);
  lap_lds(&T->A5[0][0][0],18,16,&T->A6[0][0][0],10,tid,256);
  __syncthreads();
  float v5 = diff_lds(&T->A5[0][0][0],18,16,tid,256);
  float v6 = 0.f;
  for (int f=tid; f<64; f+=256){
    float ch = T->A6[0][f>>3][f&7];
    float cl = T->A6[1][f>>3][f&7];
    float d = __fdividef(ch, fabsf(ch)+SIG1) - __fdividef(cl, fabsf(cl)+SIG1);
    v6 += d*d;
  }
  float vs[4] = {v3, v4, v5, v6};
  #pragma unroll
  for (int k=0;k<4;k++){
    float v = vs[k];
    #pragma unroll
    for (int off=32; off>0; off>>=1) v += __shfl_down(v, off);
    if ((tid&63)==0) T->red[tid>>6] = v;
    __syncthreads();
    if (tid==0)
      accum[(3+k)*16 + b] = T->red[0]+T->red[1]+T->red[2]+T->red[3];
    __syncthreads();
  }
}

// ================= finalize =================
__global__ __launch_bounds__(64)
void k_d6(const float* __restrict__ p0, const float* __restrict__ p1,
          const float* __restrict__ p2s, const float* __restrict__ accum,
          float* __restrict__ out){
  __shared__ float fin[16];
  int t = threadIdx.x;
  if (t < 16){
    float a0=0.f, a1=0.f, a2=0.f;
    for (int j=0;j<64;j++) a0 += p0[t*64+j];
    for (int j=0;j<32;j++) a1 += p1[t*32+j];
    for (int j=0;j<16;j++) a2 += p2s[t*16+j];
    float m = powf(a0*(1.0f/262144.0f), 0.3f)
            + powf(a1*(1.0f/65536.0f), 0.3f)
            + powf(a2*(1.0f/16384.0f), 0.3f);
    #pragma unroll
    for (int k=3;k<7;k++){
      int hw = (512>>k)*(512>>k);
      m += powf(accum[k*16+t]/(float)hw, 0.3f);
    }
    m *= (1.0f/7.0f);
    fin[t] = powf(m, 1.6666666666666667f);
  }
  __syncthreads();
  if (t == 0){
    float s = 0.f;
    #pragma unroll
    for (int i=0;i<16;i++) s += fin[i];
    out[0] = s * (1.0f/16.0f);
  }
}

extern "C" void kernel_launch(void* const* d_in, const int* in_sizes, int n_in,
                              void* d_out, int out_size, void* d_ws, size_t ws_size,
                              hipStream_t stream){
  const float* h = (const float*)d_in[0];
  const float* l = (const float*)d_in[1];
  float* out = (float*)d_out;
  float* ws = (float*)d_ws;

  float* g1 = ws;                         // 32 * 260*264
  float* g2 = g1 + 2196480;               // 32 * 132*136
  float* g3 = g2 + 574464;                // 32 * 68*72
  float* accum = g3 + 156672;             // 112 ([48..111] written by tail)
  float* p0 = accum + 112;                // 1024 level-0 block partials (64/img)
  float* p1 = p0 + 1024;                  // 512 level-1 (32/img)
  float* p2s = p1 + 512;                  // 256 level-2 (16/img)

  const size_t ld1  = (20*520 + 20*256)*sizeof(float);                 // 62080
  const size_t lf0  = (2*20*264 + 2*12*136 + 4)*sizeof(float);         // 55312
  const size_t ldn1 = (20*264 + 20*128)*sizeof(float);                 // 31360
  const size_t lf1  = (2*12*264 + 2*8*136 + 4)*sizeof(float);          // 34064
  const size_t ldn2 = (20*136 + 20*64)*sizeof(float);                  // 16000
  const size_t lf2  = (2*12*136 + 2*8*72 + 4)*sizeof(float);           // 17680

  k_d1        <<<dim3(32,32),   256, ld1,  stream>>>(h, l, g1);
  k_fused0    <<<dim3(2,32,16), 256, lf0,  stream>>>(h, l, g1, p0);
  k_down<256> <<<dim3(16,32),   256, ldn1, stream>>>(g1, g2);
  k_fused1    <<<dim3(32,16),   256, lf1,  stream>>>(g1, g2, p1);
  k_down<128> <<<dim3(8,32),    256, ldn2, stream>>>(g2, g3);
  k_fused2    <<<dim3(16,16),   256, lf2,  stream>>>(g2, g3, p2s);
  k_tail      <<<16, 256, sizeof(TS), stream>>>(g3, accum);
  k_d6        <<<1, 64, 0, stream>>>(p0, p1, p2s, accum, out);
}

// Round 13
// 187.399 us; speedup vs baseline: 1.0008x; 1.0008x over previous
//
#include <hip/hip_runtime.h>

#define SIG0 0.17f
#define SIG1 4.86f

__device__ __constant__ float c_filt0[25] = {
  0.04f,0.04f,0.05f,0.04f,0.04f,
  0.04f,0.03f,0.04f,0.03f,0.04f,
  0.05f,0.04f,0.05f,0.04f,0.05f,
  0.04f,0.03f,0.04f,0.03f,0.04f,
  0.04f,0.04f,0.05f,0.04f,0.04f};
__device__ __constant__ float c_f1d[5] = {0.05f,0.25f,0.4f,0.25f,0.05f};

static __device__ __forceinline__ int iclamp(int v, int lo, int hi){
  return v < lo ? lo : (v > hi ? hi : v);
}
static __device__ __forceinline__ float4 gamma4(float4 v){
  const float e = 0.3846153846153846f;
  v.x = __powf(v.x, e); v.y = __powf(v.y, e);
  v.z = __powf(v.z, e); v.w = __powf(v.w, e);
  return v;
}

// Padded level buffers: size S stored (S+4) x (S+8); logical (y,x) at [(y+2)*(S+8)+(x+4)].
// g1: S=256 stride 264 (img 68640); g2: S=128 stride 136 (17952); g3: S=64 stride 72 (4896)

// ================= k_d1: gamma + down0. out tile 256 wide x 8 tall. grid (32 yt, 32 img) ======
__global__ __launch_bounds__(256)
void k_d1(const float* __restrict__ hin, const float* __restrict__ lin,
          float* __restrict__ g1){
  extern __shared__ float sm[];
  float* ST = sm;            // [20][520]
  float* HS = sm + 20*520;   // [20][256]
  int bx = blockIdx.x, z = blockIdx.y;
  const float* in = (z<16)? hin + (size_t)z*262144 : lin + (size_t)(z-16)*262144;
  float* out0 = g1 + (size_t)z*68640;
  int t = threadIdx.x;
  for (int f=t; f<2560; f+=256){             // 20 rows x 128 chunks
    int r = f>>7, ch = f&127;
    int yy = iclamp(16*bx-2+r, 0, 511);
    float4 v = *(const float4*)&in[(size_t)yy*512 + 4*ch];
    *(float4*)&ST[r*520 + 4 + 4*ch] = gamma4(v);
  }
  __syncthreads();
  if (t < 20){
    float vl = ST[t*520 + 4],  vr = ST[t*520 + 515];
    float4 v4l = {vl,vl,vl,vl}, v4r = {vr,vr,vr,vr};
    *(float4*)&ST[t*520 + 0]   = v4l;
    *(float4*)&ST[t*520 + 516] = v4r;
  }
  __syncthreads();
  for (int f=t; f<5120; f+=256){             // 20 x 256 h-pass
    int r = f>>8, xo = f&255;
    const float* rp = &ST[r*520 + 2*xo + 2];
    HS[r*256 + xo] = 0.05f*rp[0]+0.25f*rp[1]+0.4f*rp[2]+0.25f*rp[3]+0.05f*rp[4];
  }
  __syncthreads();
  for (int f=t; f<2048; f+=256){             // 8 x 256 v-pass + padded write
    int yo = f>>8, X = f&255;
    int Y = 8*bx + yo;
    float v = 0.05f*HS[(2*yo)*256+X]+0.25f*HS[(2*yo+1)*256+X]+0.4f*HS[(2*yo+2)*256+X]
            +0.25f*HS[(2*yo+3)*256+X]+0.05f*HS[(2*yo+4)*256+X];
    int rlo=(Y==0)?0:(Y+2), rhi=(Y==255)?259:(Y+2);
    int clo=(X==0)?0:(X+4), chi=(X==255)?263:(X+4);
    for (int rr=rlo; rr<=rhi; rr++)
      for (int cc=clo; cc<=chi; cc++)
        out0[(size_t)rr*264+cc] = v;
  }
}

// ================= generic down: padded in (SIN) -> padded out (SIN/2). tile SO x 8 ==========
template<int SIN>
__global__ __launch_bounds__(256)
void k_down(const float* __restrict__ gin, float* __restrict__ gout){
  constexpr int WI = SIN+8, SO = SIN/2, PO = SO+8;
  constexpr int CH = WI/4;
  extern __shared__ float sm[];
  float* ST = sm;              // [20][WI]
  float* HS = sm + 20*WI;      // [20][SO]
  int bx = blockIdx.x, z = blockIdx.y;
  const float* in0 = gin + (size_t)z * (size_t)((SIN+4)*WI);
  float* out0 = gout + (size_t)z * (size_t)((SO+4)*PO);
  int t = threadIdx.x;
  for (int f=t; f<20*CH; f+=256){
    int r = f/CH, ch = f - r*CH;
    *(float4*)&ST[r*WI + 4*ch] = *(const float4*)&in0[(size_t)(16*bx + r)*WI + 4*ch];
  }
  __syncthreads();
  for (int f=t; f<20*SO; f+=256){
    int r = f/SO, xo = f - r*SO;
    const float* rp = &ST[r*WI + 2*xo + 2];
    HS[r*SO + xo] = 0.05f*rp[0]+0.25f*rp[1]+0.4f*rp[2]+0.25f*rp[3]+0.05f*rp[4];
  }
  __syncthreads();
  for (int f=t; f<8*SO; f+=256){
    int yo = f/SO, X = f - yo*SO;
    int Y = 8*bx + yo;
    float v = 0.05f*HS[(2*yo)*SO+X]+0.25f*HS[(2*yo+1)*SO+X]+0.4f*HS[(2*yo+2)*SO+X]
            +0.25f*HS[(2*yo+3)*SO+X]+0.05f*HS[(2*yo+4)*SO+X];
    int rlo=(Y==0)?0:(Y+2), rhi=(Y==SO-1)?(SO+3):(Y+2);
    int clo=(X==0)?0:(X+4), chi=(X==SO-1)?(SO+7):(X+4);
    for (int rr=rlo; rr<=rhi; rr++)
      for (int cc=clo; cc<=chi; cc++)
        out0[(size_t)rr*PO+cc] = v;
  }
}

// ================= fused body: lap + fixes + den + diff + reduce ===========================
// GAMMA=1: a0/a1 raw SIMGxSIMG inputs; GAMMA=0: a0/a1 padded buffers (stride SIMG+8, TW==SIMG).
// REGISTER HYGIENE: no type-punned stores into local float arrays (SROA-safe).
template<int GAMMA, int SIMG, int TW, int TH>
__device__ __forceinline__ void fused_body(
    const float* __restrict__ a0, const float* __restrict__ a1,
    const float* __restrict__ s10, const float* __restrict__ s11,
    int xt, int yt, float* __restrict__ out_slot)
{
  constexpr int WL  = TW + 8;         // sg row length
  constexpr int W1L = TW/2 + 8;       // s1 LDS row length
  constexpr int PS1 = SIMG/2 + 8;     // s1 BUFFER stride
  constexpr int NR  = TH + 4;         // sg rows
  constexpr int NR1 = TH/2 + 4;       // s1 rows
  constexpr int PRS = NR/2;           // p2 row pairs
  constexpr int NSEG= WL/8;           // p2 col segs
  constexpr int NQX = TW/4;
  constexpr int LQX = (NQX==64)?6:5;
  constexpr int QY  = TH/2;
  constexpr int CH  = WL/4;
  constexpr int CH1 = W1L/4;
  extern __shared__ float sm[];
  float* SG  = sm;                    // [2][NR][WL]
  float* S1L = sm + 2*NR*WL;          // [2][NR1][W1L]
  float* RED = S1L + 2*NR1*W1L;       // [4]
  const int t = threadIdx.x;
  const int x0 = TW*xt, y0 = TH*yt;

  // ---- p1a: stage sg ----
  if (GAMMA){
    for (int f=t; f<2*NR*CH; f+=256){
      int img = f >= NR*CH; int rem = img ? f - NR*CH : f;
      int rr = rem/CH, ch = rem - rr*CH;
      int yy = iclamp(y0-2+rr, 0, SIMG-1);
      int xb = x0 - 4 + 4*ch;
      const float* rp = (img ? a1 : a0) + (size_t)yy*SIMG;
      float4 v;
      if (xb >= 0 && xb <= SIMG-4) v = *(const float4*)&rp[xb];
      else { v.x=rp[iclamp(xb,0,SIMG-1)]; v.y=rp[iclamp(xb+1,0,SIMG-1)];
             v.z=rp[iclamp(xb+2,0,SIMG-1)]; v.w=rp[iclamp(xb+3,0,SIMG-1)]; }
      *(float4*)&SG[(img*NR+rr)*WL + 4*ch] = gamma4(v);
    }
  } else {
    for (int f=t; f<2*NR*CH; f+=256){
      int img = f >= NR*CH; int rem = img ? f - NR*CH : f;
      int rr = rem/CH, ch = rem - rr*CH;
      const float* src = img ? a1 : a0;
      *(float4*)&SG[(img*NR+rr)*WL + 4*ch] =
          *(const float4*)&src[(size_t)(y0+rr)*WL + 4*ch];
    }
  }
  // ---- p1b: stage s1 ----
  for (int f=t; f<2*NR1*CH1; f+=256){
    int img = f >= NR1*CH1; int rem = img ? f - NR1*CH1 : f;
    int ro = rem/CH1, ch = rem - ro*CH1;
    const float* src = img ? s11 : s10;
    *(float4*)&S1L[(img*NR1+ro)*W1L + 4*ch] =
        *(const float4*)&src[(size_t)(y0/2+ro)*PS1 + x0/2 + 4*ch];
  }
  __syncthreads();

  // ---- p2: lap in place; unit = (img, row-pair p, 8-col seg q) ----
  for (int f=t; f<2*PRS*NSEG; f+=256){
    int img = f >= PRS*NSEG; int rem = img ? f - PRS*NSEG : f;
    int p = rem/NSEG, q = rem - p*NSEG;
    const float* s1b = S1L + img*NR1*W1L;
    float A[8], B[8], C[8];
    {
      const float* pr = s1b + p*W1L + 4*q;
      float4 t0 = *(const float4*)&pr[0];
      float4 t1 = *(const float4*)&pr[4];
      A[0]=t0.x; A[1]=t0.y; A[2]=t0.z; A[3]=t0.w;
      A[4]=t1.x; A[5]=t1.y; A[6]=t1.z; A[7]=t1.w;
    }
    {
      const float* pr = s1b + (p+1)*W1L + 4*q;
      float4 t0 = *(const float4*)&pr[0];
      float4 t1 = *(const float4*)&pr[4];
      B[0]=t0.x; B[1]=t0.y; B[2]=t0.z; B[3]=t0.w;
      B[4]=t1.x; B[5]=t1.y; B[6]=t1.z; B[7]=t1.w;
    }
    {
      const float* pr = s1b + (p+2)*W1L + 4*q;
      float4 t0 = *(const float4*)&pr[0];
      float4 t1 = *(const float4*)&pr[4];
      C[0]=t0.x; C[1]=t0.y; C[2]=t0.z; C[3]=t0.w;
      C[4]=t1.x; C[5]=t1.y; C[6]=t1.z; C[7]=t1.w;
    }
    float ue[8], uo[8];
    #pragma unroll
    for (int j=0;j<4;j++){
      float hEA = 0.05f*A[j+1]+0.4f*A[j+2]+0.05f*A[j+3];
      float hEB = 0.05f*B[j+1]+0.4f*B[j+2]+0.05f*B[j+3];
      float hEC = 0.05f*C[j+1]+0.4f*C[j+2]+0.05f*C[j+3];
      float hOA = 0.25f*(A[j+2]+A[j+3]);
      float hOB = 0.25f*(B[j+2]+B[j+3]);
      float hOC = 0.25f*(C[j+2]+C[j+3]);
      ue[2*j]   = 0.2f*hEA + 1.6f*hEB + 0.2f*hEC;
      ue[2*j+1] = 0.2f*hOA + 1.6f*hOB + 0.2f*hOC;
      uo[2*j]   = hEB + hEC;
      uo[2*j+1] = hOB + hOC;
    }
    float* re = SG + (img*NR + 2*p)*WL + 8*q;
    float* ro_ = SG + (img*NR + 2*p+1)*WL + 8*q;
    {
      float4 e0 = *(float4*)&re[0];
      float4 e1 = *(float4*)&re[4];
      e0.x -= ue[0]; e0.y -= ue[1]; e0.z -= ue[2]; e0.w -= ue[3];
      e1.x -= ue[4]; e1.y -= ue[5]; e1.z -= ue[6]; e1.w -= ue[7];
      *(float4*)&re[0] = e0; *(float4*)&re[4] = e1;
    }
    {
      float4 o0 = *(float4*)&ro_[0];
      float4 o1 = *(float4*)&ro_[4];
      o0.x -= uo[0]; o0.y -= uo[1]; o0.z -= uo[2]; o0.w -= uo[3];
      o1.x -= uo[4]; o1.y -= uo[5]; o1.z -= uo[6]; o1.w -= uo[7];
      *(float4*)&ro_[0] = o0; *(float4*)&ro_[4] = o1;
    }
  }
  __syncthreads();

  // ---- replicate fixes: rows (y-edges), then cols (x-edges) ----
  {
    bool top = (y0 == 0), bot = (y0 + TH == SIMG);
    if (top | bot){
      for (int f=t; f<2*CH; f+=256){
        int img = f >= CH; int ch = img ? f - CH : f;
        float* base = SG + img*NR*WL;
        if (top){ float4 v = *(float4*)&base[2*WL + 4*ch];
          *(float4*)&base[0*WL + 4*ch] = v; *(float4*)&base[1*WL + 4*ch] = v; }
        if (bot){ float4 v = *(float4*)&base[(TH+1)*WL + 4*ch];
          *(float4*)&base[(TH+2)*WL + 4*ch] = v; *(float4*)&base[(TH+3)*WL + 4*ch] = v; }
      }
    }
  }
  __syncthreads();
  {
    bool lft = (x0 == 0), rgt = (x0 + TW == SIMG);
    if ((lft | rgt) && t < 2*NR){
      int img = t >= NR; int r = img ? t - NR : t;
      float* row = SG + (img*NR + r)*WL;
      if (lft){ float v = row[4];    float4 v4 = {v,v,v,v}; *(float4*)&row[0]    = v4; }
      if (rgt){ float v = row[WL-5]; float4 v4 = {v,v,v,v}; *(float4*)&row[WL-4] = v4; }
    }
  }
  __syncthreads();

  // ---- p3: box-trick den conv + diff. unit = (img, qx, qy) 4x2 quad ----
  float vacc = 0.f;
  constexpr int P3N = 2*NQX*QY;
  #pragma unroll
  for (int k=0; k<P3N/256; k++){
    int u = t + 256*k;
    int img = u & 1;
    int quad = u >> 1;
    int qx = quad & (NQX-1);
    int qy = quad >> LQX;
    const float* sgb = SG + img*NR*WL;
    int cb = 4*qx, rb = 2*qy;
    float T0[4]={0,0,0,0}, T1[4]={0,0,0,0};
    float s5a[4], s5b[4], s3a[4], s3b[4], n0[4], n1[4];
    #pragma unroll
    for (int r=0;r<6;r++){
      const float* rp = &sgb[(rb+r)*WL + cb];
      float4 t0 = *(const float4*)&rp[0];
      float4 t1 = *(const float4*)&rp[4];
      float4 t2 = *(const float4*)&rp[8];
      float w[12];
      w[0]=t0.x; w[1]=t0.y; w[2]=t0.z;  w[3]=t0.w;
      w[4]=t1.x; w[5]=t1.y; w[6]=t1.z;  w[7]=t1.w;
      w[8]=t2.x; w[9]=t2.y; w[10]=t2.z; w[11]=t2.w;
      float aw[8];
      #pragma unroll
      for (int j=0;j<8;j++) aw[j] = fabsf(w[j+2]);
      float h0 = ((aw[0]+aw[1])+(aw[2]+aw[3]))+aw[4];
      float h1 = h0 - aw[0] + aw[5];
      float h2 = h1 - aw[1] + aw[6];
      float h3 = h2 - aw[2] + aw[7];
      float hh[4] = {h0,h1,h2,h3};
      if (r<=4){
        #pragma unroll
        for (int c=0;c<4;c++) T0[c] += hh[c];
      }
      if (r>=1){
        #pragma unroll
        for (int c=0;c<4;c++) T1[c] += hh[c];
      }
      if (r==0){
        #pragma unroll
        for (int c=0;c<4;c++) s5a[c] = aw[c+2];
      }
      if (r==1){
        #pragma unroll
        for (int c=0;c<4;c++){ s3a[c] = aw[c+1]+aw[c+3]; s5b[c] = aw[c+2]; }
      }
      if (r==2){
        #pragma unroll
        for (int c=0;c<4;c++){ s5a[c] += aw[c]+aw[c+2]+aw[c+4]; n0[c]=w[c+4]; s3b[c] = aw[c+1]+aw[c+3]; }
      }
      if (r==3){
        #pragma unroll
        for (int c=0;c<4;c++){ s3a[c] += aw[c+1]+aw[c+3]; s5b[c] += aw[c]+aw[c+2]+aw[c+4]; n1[c]=w[c+4]; }
      }
      if (r==4){
        #pragma unroll
        for (int c=0;c<4;c++){ s5a[c] += aw[c+2]; s3b[c] += aw[c+1]+aw[c+3]; }
      }
      if (r==5){
        #pragma unroll
        for (int c=0;c<4;c++) s5b[c] += aw[c+2];
      }
    }
    float qv[8];
    #pragma unroll
    for (int c=0;c<4;c++){
      float d0 = SIG0 + 0.04f*T0[c] + 0.01f*s5a[c] - 0.01f*s3a[c];
      float d1 = SIG0 + 0.04f*T1[c] + 0.01f*s5b[c] - 0.01f*s3b[c];
      qv[c]   = __fdividef(n0[c], d0);
      qv[4+c] = __fdividef(n1[c], d1);
    }
    #pragma unroll
    for (int i=0;i<8;i++){
      float o = __shfl_xor(qv[i], 1);
      float d = qv[i] - o;
      vacc += d*d;
    }
  }
  if (t & 1) vacc = 0.f;   // count each img pair once
  #pragma unroll
  for (int off=32; off>0; off>>=1) vacc += __shfl_down(vacc, off);
  if ((t&63)==0) RED[t>>6] = vacc;
  __syncthreads();
  if (t==0)
    out_slot[0] = RED[0]+RED[1]+RED[2]+RED[3];
}

// ---- fused wrappers ----
__global__ __launch_bounds__(256)
void k_fused0(const float* __restrict__ h, const float* __restrict__ l,
              const float* __restrict__ g1, float* __restrict__ p0){
  int xt = blockIdx.x, yt = blockIdx.y, z = blockIdx.z;
  fused_body<1,512,256,16>(h + (size_t)z*262144, l + (size_t)z*262144,
                           g1 + (size_t)z*68640, g1 + (size_t)(z+16)*68640,
                           xt, yt, p0 + z*64 + yt*2 + xt);
}
__global__ __launch_bounds__(256)
void k_fused1(const float* __restrict__ g1, const float* __restrict__ g2,
              float* __restrict__ p1){
  int yt = blockIdx.x, z = blockIdx.y;
  fused_body<0,256,256,8>(g1 + (size_t)z*68640, g1 + (size_t)(z+16)*68640,
                          g2 + (size_t)z*17952, g2 + (size_t)(z+16)*17952,
                          0, yt, p1 + z*32 + yt);
}
__global__ __launch_bounds__(256)
void k_fused2(const float* __restrict__ g2, const float* __restrict__ g3,
              float* __restrict__ p2s){
  int yt = blockIdx.x, z = blockIdx.y;
  fused_body<0,128,128,8>(g2 + (size_t)z*17952, g2 + (size_t)(z+16)*17952,
                          g3 + (size_t)z*4896, g3 + (size_t)(z+16)*4896,
                          0, yt, p2s + z*16 + yt);
}

// ================= tail (levels 3..6) =================
struct TS {
  float A3[2][64][66];
  float A4[2][32][34];
  float A5[2][16][18];
  float A6[2][8][10];
  float red[4];
};

static __device__ __forceinline__ void down_lds(const float* Ain, int ldi, int Sin,
                                                float* Aout, int ldo, int Sout,
                                                int tid, int NT){
  int tot = 2*Sout*Sout;
  for (int f=tid; f<tot; f+=NT){
    int img = f/(Sout*Sout), rem = f%(Sout*Sout), y=rem/Sout, x=rem%Sout;
    const float* A = Ain + img*Sin*ldi;
    float s=0.f;
    #pragma unroll
    for (int i=0;i<5;i++){
      int yy=iclamp(2*y+i-2,0,Sin-1);
      float rs=0.f;
      #pragma unroll
      for (int j=0;j<5;j++){
        int xx=iclamp(2*x+j-2,0,Sin-1);
        rs += c_f1d[j]*A[yy*ldi+xx];
      }
      s += c_f1d[i]*rs;
    }
    Aout[img*Sout*ldo + y*ldo + x] = s;
  }
}
static __device__ __forceinline__ void lap_lds(float* Ak, int ldk, int S,
                                               const float* Ag, int ldg,
                                               int tid, int NT){
  int Sg = S>>1;
  int tot = 2*S*S;
  for (int f=tid; f<tot; f+=NT){
    int img=f/(S*S), rem=f%(S*S), y=rem/S, x=rem%S;
    const float* G = Ag + img*Sg*ldg;
    int y2=y>>1, x2=x>>1;
    int ry0,ry1,ry2; float wy0,wy1,wy2;
    if (!(y&1)){ ry0=iclamp(y2-1,0,Sg-1); ry1=y2; ry2=iclamp(y2+1,0,Sg-1); wy0=0.2f; wy1=1.6f; wy2=0.2f; }
    else { ry0=y2; ry1=iclamp(y2+1,0,Sg-1); ry2=y2; wy0=1.f; wy1=1.f; wy2=0.f; }
    int cx0,cx1,cx2; float wx0,wx1,wx2;
    if (!(x&1)){ cx0=iclamp(x2-1,0,Sg-1); cx1=x2; cx2=iclamp(x2+1,0,Sg-1); wx0=0.05f; wx1=0.4f; wx2=0.05f; }
    else { cx0=x2; cx1=iclamp(x2+1,0,Sg-1); cx2=x2; wx0=0.25f; wx1=0.25f; wx2=0.f; }
    float u0 = wx0*G[ry0*ldg+cx0]+wx1*G[ry0*ldg+cx1]+wx2*G[ry0*ldg+cx2];
    float u1 = wx0*G[ry1*ldg+cx0]+wx1*G[ry1*ldg+cx1]+wx2*G[ry1*ldg+cx2];
    float u2 = wx0*G[ry2*ldg+cx0]+wx1*G[ry2*ldg+cx1]+wx2*G[ry2*ldg+cx2];
    Ak[img*S*ldk + y*ldk + x] -= wy0*u0+wy1*u1+wy2*u2;
  }
}
static __device__ __forceinline__ float diff_lds(const float* A, int ld, int S,
                                                 int tid, int NT){
  float v=0.f;
  const float* Ah = A;
  const float* Al = A + S*ld;
  for (int f=tid; f<S*S; f+=NT){
    int y=f/S, x=f%S;
    float dh=SIG0, dl=SIG0;
    #pragma unroll
    for (int i=0;i<5;i++){
      int yy=iclamp(y+i-2,0,S-1);
      #pragma unroll
      for (int j=0;j<5;j++){
        int xx=iclamp(x+j-2,0,S-1);
        float w=c_filt0[i*5+j];
        dh += w*fabsf(Ah[yy*ld+xx]);
        dl += w*fabsf(Al[yy*ld+xx]);
      }
    }
    float d = __fdividef(Ah[y*ld+x],dh) - __fdividef(Al[y*ld+x],dl);
    v += d*d;
  }
  return v;
}

__global__ __launch_bounds__(256)
void k_tail(const float* __restrict__ g3, float* __restrict__ accum){
  extern __shared__ char smem[];
  TS* T = (TS*)smem;
  int b = blockIdx.x;
  int tid = threadIdx.x;
  const float* s0  = g3 + (size_t)b*4896 + 148;
  const float* s1p = g3 + (size_t)(b+16)*4896 + 148;
  for (int f=tid; f<2*4096; f+=256){
    int img=f>>12, rem=f&4095, r=rem>>6, c=rem&63;
    T->A3[img][r][c] = (img? s1p : s0)[(size_t)r*72+c];
  }
  __syncthreads();
  down_lds(&T->A3[0][0][0],66,64,&T->A4[0][0][0],34,32,tid,256);
  __syncthreads();
  down_lds(&T->A4[0][0][0],34,32,&T->A5[0][0][0],18,16,tid,256);
  __syncthreads();
  down_lds(&T->A5[0][0][0],18,16,&T->A6[0][0][0],10,8,tid,256);
  __syncthreads();
  lap_lds(&T->A3[0][0][0],66,64,&T->A4[0][0][0],34,tid,256);
  __syncthreads();
  float v3 = diff_lds(&T->A3[0][0][0],66,64,tid,256);
  lap_lds(&T->A4[0][0][0],34,32,&T->A5[0][0][0],18,tid,256);
  __syncthreads();
  float v4 = diff_lds(&T->A4[0][0][0],34,32,tid,256);
  lap_lds(&T->A5[0][0][0],18,16,&T->A6[0][0][0],10,tid,256);
  __syncthreads();
  float v5 = diff_lds(&T->A5[0][0][0],18,16,tid,256);
  float v6 = 0.f;
  for (int f=tid; f<64; f+=256){
    float ch = T->A6[0][f>>3][f&7];
    float cl = T->A6[1][f>>3][f&7];
    float d = __fdividef(ch, fabsf(ch)+SIG1) - __fdividef(cl, fabsf(cl)+SIG1);
    v6 += d*d;
  }
  float vs[4] = {v3, v4, v5, v6};
  #pragma unroll
  for (int k=0;k<4;k++){
    float v = vs[k];
    #pragma unroll
    for (int off=32; off>0; off>>=1) v += __shfl_down(v, off);
    if ((tid&63)==0) T->red[tid>>6] = v;
    __syncthreads();
    if (tid==0)
      accum[(3+k)*16 + b] = T->red[0]+T->red[1]+T->red[2]+T->red[3];
    __syncthreads();
  }
}

// ================= finalize =================
__global__ __launch_bounds__(64)
void k_d6(const float* __restrict__ p0, const float* __restrict__ p1,
          const float* __restrict__ p2s, const float* __restrict__ accum,
          float* __restrict__ out){
  __shared__ float fin[16];
  int t = threadIdx.x;
  if (t < 16){
    float a0=0.f, a1=0.f, a2=0.f;
    for (int j=0;j<64;j++) a0 += p0[t*64+j];
    for (int j=0;j<32;j++) a1 += p1[t*32+j];
    for (int j=0;j<16;j++) a2 += p2s[t*16+j];
    float m = powf(a0*(1.0f/262144.0f), 0.3f)
            + powf(a1*(1.0f/65536.0f), 0.3f)
            + powf(a2*(1.0f/16384.0f), 0.3f);
    #pragma unroll
    for (int k=3;k<7;k++){
      int hw = (512>>k)*(512>>k);
      m += powf(accum[k*16+t]/(float)hw, 0.3f);
    }
    m *= (1.0f/7.0f);
    fin[t] = powf(m, 1.6666666666666667f);
  }
  __syncthreads();
  if (t == 0){
    float s = 0.f;
    #pragma unroll
    for (int i=0;i<16;i++) s += fin[i];
    out[0] = s * (1.0f/16.0f);
  }
}

extern "C" void kernel_launch(void* const* d_in, const int* in_sizes, int n_in,
                              void* d_out, int out_size, void* d_ws, size_t ws_size,
                              hipStream_t stream){
  const float* h = (const float*)d_in[0];
  const float* l = (const float*)d_in[1];
  float* out = (float*)d_out;
  float* ws = (float*)d_ws;

  float* g1 = ws;                         // 32 * 260*264
  float* g2 = g1 + 2196480;               // 32 * 132*136
  float* g3 = g2 + 574464;                // 32 * 68*72
  float* accum = g3 + 156672;             // 112 ([48..111] written by tail)
  float* p0 = accum + 112;                // 1024 level-0 block partials (64/img)
  float* p1 = p0 + 1024;                  // 512 level-1 (32/img)
  float* p2s = p1 + 512;                  // 256 level-2 (16/img)

  const size_t ld1  = (20*520 + 20*256)*sizeof(float);                 // 62080
  const size_t lf0  = (2*20*264 + 2*12*136 + 4)*sizeof(float);         // 55312
  const size_t ldn1 = (20*264 + 20*128)*sizeof(float);                 // 31360
  const size_t lf1  = (2*12*264 + 2*8*136 + 4)*sizeof(float);          // 34064
  const size_t ldn2 = (20*136 + 20*64)*sizeof(float);                  // 16000
  const size_t lf2  = (2*12*136 + 2*8*72 + 4)*sizeof(float);           // 17680

  k_d1        <<<dim3(32,32),   256, ld1,  stream>>>(h, l, g1);
  k_fused0    <<<dim3(2,32,16), 256, lf0,  stream>>>(h, l, g1, p0);
  k_down<256> <<<dim3(16,32),   256, ldn1, stream>>>(g1, g2);
  k_fused1    <<<dim3(32,16),   256, lf1,  stream>>>(g1, g2, p1);
  k_down<128> <<<dim3(8,32),    256, ldn2, stream>>>(g2, g3);
  k_fused2    <<<dim3(16,16),   256, lf2,  stream>>>(g2, g3, p2s);
  k_tail      <<<16, 256, sizeof(TS), stream>>>(g3, accum);
  k_d6        <<<1, 64, 0, stream>>>(p0, p1, p2s, accum, out);
}